// Round 8
// baseline (248.990 us; speedup 1.0000x reference)
//
#include <hip/hip_runtime.h>
#include <hip/hip_bf16.h>
#include <math.h>

#define NEG_SLOPE 0.2f
#define BUCK_BITS 5
#define BUCK_NODES 32             // dst nodes per fine bucket
#define CAP 800                   // fine bucket capacity (mean 512 + ~12.7 sigma)
#define SRC_MASK 0x1FFFFFF        // src field in fine record (low 25 bits)
#define NBUK_MAX 3200

#define CBITS 8
#define CNODES 256                // dst nodes per coarse bucket (= 8 fine)
#define CAPC 4672                 // coarse capacity (mean 4096 + 9 sigma)
#define NC_MAX 400
#define NBIN 256                  // bin-role blocks inside fused kernel

typedef __bf16 bf16x8 __attribute__((ext_vector_type(8)));
typedef __bf16 bf16x4 __attribute__((ext_vector_type(4)));
typedef float  f32x4  __attribute__((ext_vector_type(4)));

// ---------------- K0: prep = pack W (bf16 fragment order) + zero cursors -----
// B[k][n] with n = nt*16 + (lane&15), k = kt*32 + (lane>>4)*8 + j
__global__ void prep(const float* __restrict__ W, __bf16* __restrict__ Whi,
                     unsigned int* __restrict__ fcur,
                     unsigned int* __restrict__ ccur) {
    int idx = blockIdx.x * blockDim.x + threadIdx.x;
    if (idx < NBUK_MAX) fcur[idx] = 0u;
    if (idx < NC_MAX)   ccur[idx] = 0u;
    if (idx >= 8192) return;
    int j = idx & 7, lane = (idx >> 3) & 63, nt = (idx >> 9) & 1, kt = idx >> 10;
    int q = lane >> 4, c = lane & 15;
    int k = kt * 32 + q * 8 + j;
    int n = nt * 16 + c;
    Whi[idx] = (__bf16)W[k * 32 + n];
}

// ---------------- K1: FUSED gemm_h + coarse binning --------------------------
// r6/r7 diagnosis: latency-bound at 1.65 TB/s, all pipes idle. r7's register
// prefetch was silently SUNK by the compiler (VGPR stayed 40). r8 fix: pin
// each prefetched value live via empty asm (load must complete before its
// pin) + sched_barrier(0) so compute can't hoist above the issue point ->
// 16 loads x 16 B = 256 B genuinely in flight per wave. Also drop the
// nontemporal hint on feat: L3 already serves ~40% of it (FETCH 61.6 MB <
// 102.4 MB stream); NT marks lines evict-first and fights that residency.
//
// gemm role: h = feat @ W via split-bf16 MFMA (feat = Ah+Al, Ah@Bl dropped;
//   error ~2e-3 << 0.046). Whi (16 KB, packed by prep) loaded coalesced.
//   h stored bf16 (absmax unchanged, r1). el/er fused from f32 accumulators.
// bin role: int4-vectorized hist+scan+scatter of a 6252-edge batch into 391
//   coarse buckets. Chunk per (block,bucket) ~16 recs x 4 B = 64 B contiguous
//   -> no cross-XCD sub-line amp (r3 failure mode). Record: (dst&255)<<17|src.
__global__ __launch_bounds__(256) void gemm_bin(const float* __restrict__ feat,
                                                const __bf16* __restrict__ Whi,
                                                const float* __restrict__ attn_l,
                                                const float* __restrict__ attn_r,
                                                const int* __restrict__ src,
                                                const int* __restrict__ dst,
                                                __bf16* __restrict__ hb,
                                                float* __restrict__ el,
                                                float* __restrict__ er,
                                                unsigned int* __restrict__ ccur,
                                                unsigned int* __restrict__ cbin,
                                                int N, int Ntiles, int E, int NC) {
    __shared__ bf16x8 sB[1024];   // gemm: 16 KB packed W | bin: hist/cbase
    int bid = blockIdx.x;
    int tid = threadIdx.x;
    int role, gid;
    if (bid < 2 * NBIN) { role = bid & 1; gid = bid >> 1; }
    else                { role = 0;       gid = bid - NBIN; }

    if (role == 1) {
        // ---------------- binning path (int4-vectorized) ----------------
        unsigned int* hist  = (unsigned int*)sB;      // [NC_MAX]
        unsigned int* cbase = hist + NC_MAX;          // [NC_MAX]
        int batch = (((E + NBIN - 1) / NBIN) + 3) & ~3;   // multiple of 4
        int b0 = gid * batch;
        int b1 = min(b0 + batch, E);
        int nv = (b0 < b1) ? ((b1 - b0) >> 2) : 0;    // E%4==0 -> exact
        const int4* d4 = (const int4*)(dst + b0);
        const int4* s4 = (const int4*)(src + b0);
        for (int i = tid; i < NC; i += 256) hist[i] = 0;
        __syncthreads();
        for (int i = tid; i < nv; i += 256) {
            int4 dd = d4[i];
#pragma unroll
            for (int j = 0; j < 4; j++)
                atomicAdd(&hist[((unsigned)(&dd.x)[j]) >> CBITS], 1u);
        }
        __syncthreads();
        for (int i = tid; i < NC; i += 256) {
            unsigned c = hist[i];
            cbase[i] = c ? atomicAdd(&ccur[i], c) : 0u;
            hist[i] = 0;  // reuse as local rank cursor
        }
        __syncthreads();
        for (int i = tid; i < nv; i += 256) {
            int4 dd = d4[i];
            int4 ss = s4[i];
#pragma unroll
            for (int j = 0; j < 4; j++) {
                int d = (&dd.x)[j];
                int s = (&ss.x)[j];
                unsigned cb = ((unsigned)d) >> CBITS;
                unsigned r = atomicAdd(&hist[cb], 1u);
                unsigned pos = cbase[cb] + r;
                if (pos < CAPC)  // never true for this input; guards corruption
                    cbin[(size_t)cb * CAPC + pos] =
                        ((unsigned)(d & (CNODES - 1)) << 17) | (unsigned)s;
            }
        }
        return;
    }

    // ---------------- gemm path ----------------
    for (int i = tid; i < 1024; i += 256) sB[i] = ((const bf16x8*)Whi)[i];
    __syncthreads();

    int wid  = gid * 4 + (tid >> 6);
    int lane = tid & 63;
    if (wid >= Ntiles) return;

    int c = lane & 15, q = lane >> 4;
    int row = wid * 16 + c;
    if (row >= N) row = N - 1;  // defensive clamp
    const f32x4* A = (const f32x4*)(feat + (size_t)row * 256 + q * 8);

    // prefetch ALL feat for this tile: 16 loads x 16 B = 256 B in flight/wave.
    // Empty-asm pins force each load's result live HERE (compiler cannot sink
    // the loads back into the compute loop — r7's failure, VGPR stayed 40);
    // sched_barrier(0) keeps compute from hoisting above the issue point.
    f32x4 a[16];
#pragma unroll
    for (int kt = 0; kt < 8; kt++) {
        a[2 * kt]     = A[kt * 8];
        a[2 * kt + 1] = A[kt * 8 + 1];
    }
#pragma unroll
    for (int i = 0; i < 16; i++)
        asm volatile("" : "+v"(a[i]));
    __builtin_amdgcn_sched_barrier(0);

    f32x4 acc0 = {0.f, 0.f, 0.f, 0.f};
    f32x4 acc1 = {0.f, 0.f, 0.f, 0.f};
#pragma unroll
    for (int kt = 0; kt < 8; kt++) {
        f32x4 a0 = a[2 * kt];
        f32x4 a1 = a[2 * kt + 1];
        bf16x8 ah, al;
#pragma unroll
        for (int j = 0; j < 4; j++) {
            __bf16 h0 = (__bf16)a0[j];
            __bf16 h1 = (__bf16)a1[j];
            ah[j]     = h0;
            ah[j + 4] = h1;
            al[j]     = (__bf16)(a0[j] - (float)h0);
            al[j + 4] = (__bf16)(a1[j] - (float)h1);
        }
        bf16x8 bh0 = sB[(kt * 2 + 0) * 64 + lane];
        bf16x8 bh1 = sB[(kt * 2 + 1) * 64 + lane];
        acc0 = __builtin_amdgcn_mfma_f32_16x16x32_bf16(ah, bh0, acc0, 0, 0, 0);
        acc0 = __builtin_amdgcn_mfma_f32_16x16x32_bf16(al, bh0, acc0, 0, 0, 0);
        acc1 = __builtin_amdgcn_mfma_f32_16x16x32_bf16(ah, bh1, acc1, 0, 0, 0);
        acc1 = __builtin_amdgcn_mfma_f32_16x16x32_bf16(al, bh1, acc1, 0, 0, 0);
    }

    // epilogue: store h bf16 (C/D layout: col=lane&15, row=(lane>>4)*4+reg),
    // el/er from f32 accumulators (full precision)
    float alc  = attn_l[c],      arc  = attn_r[c];
    float alc2 = attn_l[c + 16], arc2 = attn_r[c + 16];
#pragma unroll
    for (int r = 0; r < 4; r++) {
        int m = wid * 16 + q * 4 + r;
        if (m < N) {
            hb[(size_t)m * 32 + c]      = (__bf16)acc0[r];
            hb[(size_t)m * 32 + 16 + c] = (__bf16)acc1[r];
        }
        float pl = acc0[r] * alc + acc1[r] * alc2;
        float pr = acc0[r] * arc + acc1[r] * arc2;
#pragma unroll
        for (int off = 8; off >= 1; off >>= 1) {
            pl += __shfl_xor(pl, off);
            pr += __shfl_xor(pr, off);
        }
        if (c == 0 && m < N) { el[m] = pl; er[m] = pr; }
    }
}

// ---------------- K2: refine coarse buckets into 32-node fine buckets -------
// 2 blocks per coarse bucket. TWO passes over cbin (second read L2-hot)
// instead of a runtime-indexed register cache (scratch-spill hazard).
// Fine record: (dst&31)<<25 | src.
__global__ __launch_bounds__(256) void refine(const unsigned int* __restrict__ ccur,
                                              const unsigned int* __restrict__ cbin,
                                              unsigned int* __restrict__ fcur,
                                              unsigned int* __restrict__ fbin,
                                              int NC) {
    __shared__ unsigned int hist[8];
    __shared__ unsigned int basec[8];
    int blk = blockIdx.x;
    int cb = blk >> 1, seg = blk & 1;
    if (cb >= NC) return;
    int tid = threadIdx.x;
    int cnt = (int)min(ccur[cb], (unsigned)CAPC);
    int lo = (cnt * seg) >> 1;
    int hi = (cnt * (seg + 1)) >> 1;

    if (tid < 8) hist[tid] = 0;
    __syncthreads();
    const unsigned int* cp = cbin + (size_t)cb * CAPC;
    for (int i = lo + tid; i < hi; i += 256)
        atomicAdd(&hist[(cp[i] >> (17 + BUCK_BITS)) & 7], 1u);
    __syncthreads();
    if (tid < 8) {
        unsigned v = hist[tid];
        basec[tid] = v ? atomicAdd(&fcur[cb * 8 + tid], v) : 0u;
        hist[tid] = 0;  // reuse as rank cursor
    }
    __syncthreads();
    for (int i = lo + tid; i < hi; i += 256) {
        unsigned r = cp[i];
        int fb = (r >> (17 + BUCK_BITS)) & 7;
        unsigned rank = atomicAdd(&hist[fb], 1u);
        unsigned pos = basec[fb] + rank;
        if (pos < CAP)  // never true for this input; guards corruption
            fbin[(size_t)(cb * 8 + fb) * CAP + pos] =
                (((r >> 17) & (BUCK_NODES - 1)) << 25) | (r & 0x1FFFFu);
    }
}

// ---------------- K3: per-bucket counting sort + oct-lane bf16x4 gather ------
// (r2/r4/r7 measured-best core, unchanged) No max-subtraction (softmax
// shift-invariant; |e| <= ~6, exp safe). Oct of lanes covers a full 64 B bf16
// row: one cache line per edge, 8 edges in flight per wave, 3-stage reduce.
__global__ __launch_bounds__(256) void aggregate(const unsigned int* __restrict__ cursor,
                                                 const unsigned int* __restrict__ binned,
                                                 const float* __restrict__ el,
                                                 const float* __restrict__ er,
                                                 const __bf16* __restrict__ hb,
                                                 const float* __restrict__ bias,
                                                 float* __restrict__ out, int N) {
    __shared__ uint2        rw_s[CAP];      // sorted (src, w-bits)
    __shared__ unsigned int hist[BUCK_NODES];
    __shared__ int          off_s[BUCK_NODES + 1];
    __shared__ float        den[BUCK_NODES];
    __shared__ float        er_l[BUCK_NODES];

    int buck = blockIdx.x;
    int base = buck << BUCK_BITS;
    int nn = min(BUCK_NODES, N - base);
    int tid = threadIdx.x;

    int cnt = (int)min(cursor[buck], (unsigned)CAP);
    const unsigned int* eb = binned + (size_t)buck * CAP;

    if (tid < BUCK_NODES) {
        hist[tid] = 0;
        den[tid] = 0.f;
        er_l[tid] = (tid < nn) ? er[base + tid] : 0.f;
    }
    __syncthreads();

    // 1. register-cache records + histogram (single global read of binned)
    unsigned int rl[4];
    int k = 0;
    for (int i = tid; i < cnt; i += 256) {
        unsigned r = eb[i];
        rl[k++] = r;
        atomicAdd(&hist[r >> 25], 1u);
    }
    __syncthreads();

    // 2. 32-lane exclusive scan (first wave)
    if (tid < BUCK_NODES) {
        int v = (int)hist[tid];
        int orig = v;
#pragma unroll
        for (int off = 1; off < BUCK_NODES; off <<= 1) {
            int x = __shfl_up(v, off, 64);
            if (tid >= off) v += x;
        }
        off_s[tid] = v - orig;
        if (tid == BUCK_NODES - 1) off_s[BUCK_NODES] = v;
        hist[tid] = (unsigned)(v - orig);  // scatter cursor
    }
    __syncthreads();

    // 3. scatter: (src, weight) packed + denominators
    k = 0;
    for (int i = tid; i < cnt; i += 256) {
        unsigned r = rl[k++];
        int s = r & SRC_MASK;
        int d = r >> 25;
        float e = el[s] + er_l[d];
        e = (e > 0.f) ? e : NEG_SLOPE * e;
        float w = __expf(e);
        unsigned pos = atomicAdd(&hist[d], 1u);
        rw_s[pos] = make_uint2((unsigned)s, __float_as_uint(w));
        atomicAdd(&den[d], w);
    }
    __syncthreads();

    // 4. gather: wave per node; 8 lanes x bf16x4 (8 B) per edge
    int lane = tid & 63, wv = tid >> 6;
    int oct = lane >> 3, t = lane & 7;
    f32x4 b4 = *(const f32x4*)&bias[t * 4];
    for (int n = wv; n < nn; n += 4) {
        float sm = den[n];
        int s0 = off_s[n], s1 = off_s[n + 1];
        f32x4 acc = {0.f, 0.f, 0.f, 0.f};
#pragma unroll 2
        for (int j = s0 + oct; j < s1; j += 8) {
            uint2 rw = rw_s[j];
            float w = __uint_as_float(rw.y);
            bf16x4 hv = *(const bf16x4*)&hb[(size_t)rw.x * 32 + t * 4];
            acc[0] += w * (float)hv[0];
            acc[1] += w * (float)hv[1];
            acc[2] += w * (float)hv[2];
            acc[3] += w * (float)hv[3];
        }
#pragma unroll
        for (int off = 8; off <= 32; off <<= 1) {
            acc[0] += __shfl_xor(acc[0], off);
            acc[1] += __shfl_xor(acc[1], off);
            acc[2] += __shfl_xor(acc[2], off);
            acc[3] += __shfl_xor(acc[3], off);
        }
        if (lane < 8) {
            f32x4 o;
            if (sm > 0.f) {
                float inv = 1.f / sm;
                o[0] = acc[0] * inv + b4[0];
                o[1] = acc[1] * inv + b4[1];
                o[2] = acc[2] * inv + b4[2];
                o[3] = acc[3] * inv + b4[3];
            } else {
                o = b4;  // isolated node
            }
            *(f32x4*)&out[(size_t)(base + n) * 32 + t * 4] = o;
        }
    }
}

// ---------------- host launch -----------------------------------------------
static inline size_t align256(size_t x) { return (x + 255) & ~(size_t)255; }

extern "C" void kernel_launch(void* const* d_in, const int* in_sizes, int n_in,
                              void* d_out, int out_size, void* d_ws, size_t ws_size,
                              hipStream_t stream) {
    const float* feat   = (const float*)d_in[0];
    const float* W      = (const float*)d_in[1];
    const float* attn_l = (const float*)d_in[2];
    const float* attn_r = (const float*)d_in[3];
    const float* bias   = (const float*)d_in[4];
    const int* src = (const int*)d_in[5];
    const int* dst = (const int*)d_in[6];
    float* out = (float*)d_out;

    const int IN = 256;
    int N = in_sizes[0] / IN;   // 100000
    int E = in_sizes[5];        // 1600000
    (void)n_in; (void)out_size; (void)ws_size;

    int Ntiles = (N + 15) / 16;                   // 6250
    int NBUK = (N + BUCK_NODES - 1) >> BUCK_BITS; // 3125 (<= NBUK_MAX)
    int NC   = (N + CNODES - 1) >> CBITS;         // 391  (<= NC_MAX)
    int NG   = (Ntiles + 3) / 4;                  // 1563 gemm blocks

    char* p = (char*)d_ws;
    __bf16* hb     = (__bf16*)p; p += align256((size_t)N * 32 * 2);
    float* el      = (float*)p; p += align256((size_t)N * 4);
    float* er      = (float*)p; p += align256((size_t)N * 4);
    unsigned int* fcur = (unsigned int*)p; p += align256((size_t)NBUK_MAX * 4);
    unsigned int* ccur = (unsigned int*)p; p += align256((size_t)NC_MAX * 4);
    unsigned int* fbin = (unsigned int*)p; p += align256((size_t)NBUK * CAP * 4);
    unsigned int* cbin = (unsigned int*)p; p += align256((size_t)NC * CAPC * 4);
    __bf16* Whi    = (__bf16*)p; p += align256((size_t)8192 * 2);

    prep<<<33, 256, 0, stream>>>(W, Whi, fcur, ccur);
    gemm_bin<<<NG + NBIN, 256, 0, stream>>>(feat, Whi, attn_l, attn_r, src, dst,
                                            hb, el, er, ccur, cbin,
                                            N, Ntiles, E, NC);
    refine<<<NC * 2, 256, 0, stream>>>(ccur, cbin, fcur, fbin, NC);
    aggregate<<<NBUK, 256, 0, stream>>>(fcur, fbin, el, er, hb, bias, out, N);
}

// Round 9
// 226.841 us; speedup vs baseline: 1.0976x; 1.0976x over previous
//
#include <hip/hip_runtime.h>
#include <hip/hip_bf16.h>
#include <math.h>

#define NEG_SLOPE 0.2f
#define BUCK_BITS 5
#define BUCK_NODES 32             // dst nodes per fine bucket
#define CAP 800                   // fine bucket capacity (mean 512 + ~12.7 sigma)
#define SRC_MASK 0x1FFFFFF        // src field in fine record (low 25 bits)
#define NBUK_MAX 3200

#define CBITS 8
#define CNODES 256                // dst nodes per coarse bucket (= 8 fine)
#define CAPC 4672                 // coarse capacity (mean 4096 + 9 sigma)
#define NC_MAX 400
#define NBIN 256                  // bin-role blocks inside fused kernel
#define NGEMM 256                 // gemm-role blocks (4 waves each, ~6 tiles/wave)

typedef __bf16 bf16x8 __attribute__((ext_vector_type(8)));
typedef __bf16 bf16x4 __attribute__((ext_vector_type(4)));
typedef float  f32x4  __attribute__((ext_vector_type(4)));

// ---------------- K0: prep = pack W (bf16 fragment order) + zero cursors -----
// B[k][n] with n = nt*16 + (lane&15), k = kt*32 + (lane>>4)*8 + j
__global__ void prep(const float* __restrict__ W, __bf16* __restrict__ Whi,
                     unsigned int* __restrict__ fcur,
                     unsigned int* __restrict__ ccur) {
    int idx = blockIdx.x * blockDim.x + threadIdx.x;
    if (idx < NBUK_MAX) fcur[idx] = 0u;
    if (idx < NC_MAX)   ccur[idx] = 0u;
    if (idx >= 8192) return;
    int j = idx & 7, lane = (idx >> 3) & 63, nt = (idx >> 9) & 1, kt = idx >> 10;
    int q = lane >> 4, c = lane & 15;
    int k = kt * 32 + q * 8 + j;
    int n = nt * 16 + c;
    Whi[idx] = (__bf16)W[k * 32 + n];
}

// ---------------- K1: FUSED gemm_h + coarse binning --------------------------
// r6-r8 diagnosis: gemm role is latency/queue-bound (1.4-1.7 TB/s, all pipes
// idle); register prefetch CANNOT be forced through hipcc (r7: loads sunk,
// VGPR 40; r8: pins+sched_barrier -> VGPR 48, slower). r9: deep async queues
// via global_load_lds DMA staging (no VGPR cost, vmcnt-counted):
//   per wave: private 2 x 4KB LDS buffers; quarter-tile = 16 rows x 256 B.
//   Pipeline: stage(q+2) in flight while computing q; s_waitcnt vmcnt(4)
//   (never 0) + sched_barrier(0) before consuming a buffer (rule 18).
//   LDS reads conflict-mitigated by XOR swizzle byte^((row&7)<<4) applied on
//   the per-lane GLOBAL source (LDS dest must stay linear: m104/m173).
// gemm math unchanged: feat = Ah+Al split-bf16 MFMA (Ah@Bl dropped, err ~2e-3);
//   h stored bf16; el/er from f32 accumulators.
// bin role: unchanged r7 int4 version (64 B contiguous chunks per bucket).
__global__ __launch_bounds__(256) void gemm_bin(const float* __restrict__ feat,
                                                const __bf16* __restrict__ Whi,
                                                const float* __restrict__ attn_l,
                                                const float* __restrict__ attn_r,
                                                const int* __restrict__ src,
                                                const int* __restrict__ dst,
                                                __bf16* __restrict__ hb,
                                                float* __restrict__ el,
                                                float* __restrict__ er,
                                                unsigned int* __restrict__ ccur,
                                                unsigned int* __restrict__ cbin,
                                                int N, int Ntiles, int E, int NC) {
    union SM {
        struct { bf16x8 whi[1024]; float stage[4][2][1024]; } g;  // 16+32 KB
        struct { unsigned int hist[NC_MAX]; unsigned int cbase[NC_MAX]; } b;
    };
    __shared__ SM sm;

    int bid = blockIdx.x;
    int tid = threadIdx.x;
    int role = bid & 1, gid = bid >> 1;

    if (role == 1) {
        // ---------------- binning path (int4-vectorized, r7) ----------------
        unsigned int* hist  = sm.b.hist;
        unsigned int* cbase = sm.b.cbase;
        int batch = (((E + NBIN - 1) / NBIN) + 3) & ~3;   // multiple of 4
        int b0 = gid * batch;
        int b1 = min(b0 + batch, E);
        int nv = (b0 < b1) ? ((b1 - b0) >> 2) : 0;        // E%4==0 -> exact
        const int4* d4 = (const int4*)(dst + b0);
        const int4* s4 = (const int4*)(src + b0);
        for (int i = tid; i < NC; i += 256) hist[i] = 0;
        __syncthreads();
        for (int i = tid; i < nv; i += 256) {
            int4 dd = d4[i];
#pragma unroll
            for (int j = 0; j < 4; j++)
                atomicAdd(&hist[((unsigned)(&dd.x)[j]) >> CBITS], 1u);
        }
        __syncthreads();
        for (int i = tid; i < NC; i += 256) {
            unsigned c = hist[i];
            cbase[i] = c ? atomicAdd(&ccur[i], c) : 0u;
            hist[i] = 0;  // reuse as local rank cursor
        }
        __syncthreads();
        for (int i = tid; i < nv; i += 256) {
            int4 dd = d4[i];
            int4 ss = s4[i];
#pragma unroll
            for (int j = 0; j < 4; j++) {
                int d = (&dd.x)[j];
                int s = (&ss.x)[j];
                unsigned cb = ((unsigned)d) >> CBITS;
                unsigned r = atomicAdd(&hist[cb], 1u);
                unsigned pos = cbase[cb] + r;
                if (pos < CAPC)  // never true for this input; guards corruption
                    cbin[(size_t)cb * CAPC + pos] =
                        ((unsigned)(d & (CNODES - 1)) << 17) | (unsigned)s;
            }
        }
        return;
    }

    // ---------------- gemm path ----------------
    for (int i = tid; i < 1024; i += 256) sm.g.whi[i] = ((const bf16x8*)Whi)[i];
    __syncthreads();

    int wv   = tid >> 6;
    int lane = tid & 63;
    int cc = lane & 15, qd = lane >> 4;
    int swz = (cc & 7) << 4;

    int gw = gid * 4 + wv;              // global wave id, 0..1023
    int nt = (Ntiles - gw + 1023) >> 10;  // tiles for this wave (>=1 here)
    int Q  = 4 * nt;                    // quarters

    float* buf0 = &sm.g.stage[wv][0][0];
    float* buf1 = &sm.g.stage[wv][1][0];

    // stage quarter q: tile t0+ (q>>2)*1024, K-quarter q&3, into buf[q&1].
    // q >= Q clamps to last valid quarter (keeps vmcnt count fixed; result
    // unused). 4 x global_load_lds of 1 KB; per-lane swizzled global source.
    auto stage_q = [&](int q) {
        int qc = q < Q ? q : Q - 1;
        int t  = gw + ((qc >> 2) << 10);
        int kq = qc & 3;
        float* lb = (q & 1) ? buf1 : buf0;
#pragma unroll
        for (int j = 0; j < 4; j++) {
            int r = 4 * j + (lane >> 4);
            int grow = t * 16 + r;
            if (grow >= N) grow = N - 1;  // defensive clamp
            int seg = ((lane & 15) * 16) ^ ((r & 7) << 4);
            const char* sp = (const char*)feat +
                             ((size_t)grow * 256 + kq * 64) * 4 + seg;
            __builtin_amdgcn_global_load_lds(
                (const __attribute__((address_space(1))) void*)sp,
                (__attribute__((address_space(3))) void*)(lb + j * 256),
                16, 0, 0);
        }
    };

    stage_q(0);
    stage_q(1);

    float alc  = attn_l[cc],      arc  = attn_r[cc];
    float alc2 = attn_l[cc + 16], arc2 = attn_r[cc + 16];

    f32x4 acc0 = {0.f, 0.f, 0.f, 0.f};
    f32x4 acc1 = {0.f, 0.f, 0.f, 0.f};

    for (int i = 0; i < nt; i++) {
#pragma unroll
        for (int kq2 = 0; kq2 < 4; kq2++) {
            int q = i * 4 + kq2;
            asm volatile("s_waitcnt vmcnt(4)" ::: "memory");
            __builtin_amdgcn_sched_barrier(0);
            const char* lb = (const char*)((q & 1) ? buf1 : buf0);
#pragma unroll
            for (int jj = 0; jj < 2; jj++) {
                int kt = kq2 * 2 + jj;
                int so = jj * 128 + qd * 32;
                f32x4 a0 = *(const f32x4*)(lb + cc * 256 + ((so)      ^ swz));
                f32x4 a1 = *(const f32x4*)(lb + cc * 256 + ((so + 16) ^ swz));
                bf16x8 ah, al;
#pragma unroll
                for (int j = 0; j < 4; j++) {
                    __bf16 h0 = (__bf16)a0[j];
                    __bf16 h1 = (__bf16)a1[j];
                    ah[j]     = h0;
                    ah[j + 4] = h1;
                    al[j]     = (__bf16)(a0[j] - (float)h0);
                    al[j + 4] = (__bf16)(a1[j] - (float)h1);
                }
                bf16x8 bh0 = sm.g.whi[(kt * 2 + 0) * 64 + lane];
                bf16x8 bh1 = sm.g.whi[(kt * 2 + 1) * 64 + lane];
                acc0 = __builtin_amdgcn_mfma_f32_16x16x32_bf16(ah, bh0, acc0, 0, 0, 0);
                acc0 = __builtin_amdgcn_mfma_f32_16x16x32_bf16(al, bh0, acc0, 0, 0, 0);
                acc1 = __builtin_amdgcn_mfma_f32_16x16x32_bf16(ah, bh1, acc1, 0, 0, 0);
                acc1 = __builtin_amdgcn_mfma_f32_16x16x32_bf16(al, bh1, acc1, 0, 0, 0);
            }
            if (kq2 == 3) {
                // epilogue BEFORE staging, so vmcnt(4) never waits on a
                // just-issued stage. C/D layout: col=lane&15, row=q*4+reg.
                int t = gw + (i << 10);
#pragma unroll
                for (int r = 0; r < 4; r++) {
                    int m = t * 16 + qd * 4 + r;
                    if (m < N) {
                        hb[(size_t)m * 32 + cc]      = (__bf16)acc0[r];
                        hb[(size_t)m * 32 + 16 + cc] = (__bf16)acc1[r];
                    }
                    float pl = acc0[r] * alc + acc1[r] * alc2;
                    float pr = acc0[r] * arc + acc1[r] * arc2;
#pragma unroll
                    for (int off = 8; off >= 1; off >>= 1) {
                        pl += __shfl_xor(pl, off);
                        pr += __shfl_xor(pr, off);
                    }
                    if (cc == 0 && m < N) { el[m] = pl; er[m] = pr; }
                }
                acc0 = (f32x4){0.f, 0.f, 0.f, 0.f};
                acc1 = (f32x4){0.f, 0.f, 0.f, 0.f};
            }
            __builtin_amdgcn_sched_barrier(0);  // keep stage after all reads
            stage_q(q + 2);
        }
    }
}

// ---------------- K2: refine coarse buckets into 32-node fine buckets -------
// 2 blocks per coarse bucket. TWO passes over cbin (second read L2-hot).
// Fine record: (dst&31)<<25 | src.
__global__ __launch_bounds__(256) void refine(const unsigned int* __restrict__ ccur,
                                              const unsigned int* __restrict__ cbin,
                                              unsigned int* __restrict__ fcur,
                                              unsigned int* __restrict__ fbin,
                                              int NC) {
    __shared__ unsigned int hist[8];
    __shared__ unsigned int basec[8];
    int blk = blockIdx.x;
    int cb = blk >> 1, seg = blk & 1;
    if (cb >= NC) return;
    int tid = threadIdx.x;
    int cnt = (int)min(ccur[cb], (unsigned)CAPC);
    int lo = (cnt * seg) >> 1;
    int hi = (cnt * (seg + 1)) >> 1;

    if (tid < 8) hist[tid] = 0;
    __syncthreads();
    const unsigned int* cp = cbin + (size_t)cb * CAPC;
    for (int i = lo + tid; i < hi; i += 256)
        atomicAdd(&hist[(cp[i] >> (17 + BUCK_BITS)) & 7], 1u);
    __syncthreads();
    if (tid < 8) {
        unsigned v = hist[tid];
        basec[tid] = v ? atomicAdd(&fcur[cb * 8 + tid], v) : 0u;
        hist[tid] = 0;  // reuse as rank cursor
    }
    __syncthreads();
    for (int i = lo + tid; i < hi; i += 256) {
        unsigned r = cp[i];
        int fb = (r >> (17 + BUCK_BITS)) & 7;
        unsigned rank = atomicAdd(&hist[fb], 1u);
        unsigned pos = basec[fb] + rank;
        if (pos < CAP)  // never true for this input; guards corruption
            fbin[(size_t)(cb * 8 + fb) * CAP + pos] =
                (((r >> 17) & (BUCK_NODES - 1)) << 25) | (r & 0x1FFFFu);
    }
}

// ---------------- K3: per-bucket counting sort + oct-lane bf16x4 gather ------
// (r2/r4/r7 measured-best core, unchanged) No max-subtraction (softmax
// shift-invariant; |e| <= ~6, exp safe). Oct of lanes covers a full 64 B bf16
// row: one cache line per edge, 8 edges in flight per wave, 3-stage reduce.
__global__ __launch_bounds__(256) void aggregate(const unsigned int* __restrict__ cursor,
                                                 const unsigned int* __restrict__ binned,
                                                 const float* __restrict__ el,
                                                 const float* __restrict__ er,
                                                 const __bf16* __restrict__ hb,
                                                 const float* __restrict__ bias,
                                                 float* __restrict__ out, int N) {
    __shared__ uint2        rw_s[CAP];      // sorted (src, w-bits)
    __shared__ unsigned int hist[BUCK_NODES];
    __shared__ int          off_s[BUCK_NODES + 1];
    __shared__ float        den[BUCK_NODES];
    __shared__ float        er_l[BUCK_NODES];

    int buck = blockIdx.x;
    int base = buck << BUCK_BITS;
    int nn = min(BUCK_NODES, N - base);
    int tid = threadIdx.x;

    int cnt = (int)min(cursor[buck], (unsigned)CAP);
    const unsigned int* eb = binned + (size_t)buck * CAP;

    if (tid < BUCK_NODES) {
        hist[tid] = 0;
        den[tid] = 0.f;
        er_l[tid] = (tid < nn) ? er[base + tid] : 0.f;
    }
    __syncthreads();

    // 1. register-cache records + histogram (single global read of binned)
    unsigned int rl[4];
    int k = 0;
    for (int i = tid; i < cnt; i += 256) {
        unsigned r = eb[i];
        rl[k++] = r;
        atomicAdd(&hist[r >> 25], 1u);
    }
    __syncthreads();

    // 2. 32-lane exclusive scan (first wave)
    if (tid < BUCK_NODES) {
        int v = (int)hist[tid];
        int orig = v;
#pragma unroll
        for (int off = 1; off < BUCK_NODES; off <<= 1) {
            int x = __shfl_up(v, off, 64);
            if (tid >= off) v += x;
        }
        off_s[tid] = v - orig;
        if (tid == BUCK_NODES - 1) off_s[BUCK_NODES] = v;
        hist[tid] = (unsigned)(v - orig);  // scatter cursor
    }
    __syncthreads();

    // 3. scatter: (src, weight) packed + denominators
    k = 0;
    for (int i = tid; i < cnt; i += 256) {
        unsigned r = rl[k++];
        int s = r & SRC_MASK;
        int d = r >> 25;
        float e = el[s] + er_l[d];
        e = (e > 0.f) ? e : NEG_SLOPE * e;
        float w = __expf(e);
        unsigned pos = atomicAdd(&hist[d], 1u);
        rw_s[pos] = make_uint2((unsigned)s, __float_as_uint(w));
        atomicAdd(&den[d], w);
    }
    __syncthreads();

    // 4. gather: wave per node; 8 lanes x bf16x4 (8 B) per edge
    int lane = tid & 63, wv = tid >> 6;
    int oct = lane >> 3, t = lane & 7;
    f32x4 b4 = *(const f32x4*)&bias[t * 4];
    for (int n = wv; n < nn; n += 4) {
        float sm = den[n];
        int s0 = off_s[n], s1 = off_s[n + 1];
        f32x4 acc = {0.f, 0.f, 0.f, 0.f};
#pragma unroll 2
        for (int j = s0 + oct; j < s1; j += 8) {
            uint2 rw = rw_s[j];
            float w = __uint_as_float(rw.y);
            bf16x4 hv = *(const bf16x4*)&hb[(size_t)rw.x * 32 + t * 4];
            acc[0] += w * (float)hv[0];
            acc[1] += w * (float)hv[1];
            acc[2] += w * (float)hv[2];
            acc[3] += w * (float)hv[3];
        }
#pragma unroll
        for (int off = 8; off <= 32; off <<= 1) {
            acc[0] += __shfl_xor(acc[0], off);
            acc[1] += __shfl_xor(acc[1], off);
            acc[2] += __shfl_xor(acc[2], off);
            acc[3] += __shfl_xor(acc[3], off);
        }
        if (lane < 8) {
            f32x4 o;
            if (sm > 0.f) {
                float inv = 1.f / sm;
                o[0] = acc[0] * inv + b4[0];
                o[1] = acc[1] * inv + b4[1];
                o[2] = acc[2] * inv + b4[2];
                o[3] = acc[3] * inv + b4[3];
            } else {
                o = b4;  // isolated node
            }
            *(f32x4*)&out[(size_t)(base + n) * 32 + t * 4] = o;
        }
    }
}

// ---------------- host launch -----------------------------------------------
static inline size_t align256(size_t x) { return (x + 255) & ~(size_t)255; }

extern "C" void kernel_launch(void* const* d_in, const int* in_sizes, int n_in,
                              void* d_out, int out_size, void* d_ws, size_t ws_size,
                              hipStream_t stream) {
    const float* feat   = (const float*)d_in[0];
    const float* W      = (const float*)d_in[1];
    const float* attn_l = (const float*)d_in[2];
    const float* attn_r = (const float*)d_in[3];
    const float* bias   = (const float*)d_in[4];
    const int* src = (const int*)d_in[5];
    const int* dst = (const int*)d_in[6];
    float* out = (float*)d_out;

    const int IN = 256;
    int N = in_sizes[0] / IN;   // 100000
    int E = in_sizes[5];        // 1600000
    (void)n_in; (void)out_size; (void)ws_size;

    int Ntiles = (N + 15) / 16;                   // 6250
    int NBUK = (N + BUCK_NODES - 1) >> BUCK_BITS; // 3125 (<= NBUK_MAX)
    int NC   = (N + CNODES - 1) >> CBITS;         // 391  (<= NC_MAX)

    char* p = (char*)d_ws;
    __bf16* hb     = (__bf16*)p; p += align256((size_t)N * 32 * 2);
    float* el      = (float*)p; p += align256((size_t)N * 4);
    float* er      = (float*)p; p += align256((size_t)N * 4);
    unsigned int* fcur = (unsigned int*)p; p += align256((size_t)NBUK_MAX * 4);
    unsigned int* ccur = (unsigned int*)p; p += align256((size_t)NC_MAX * 4);
    unsigned int* fbin = (unsigned int*)p; p += align256((size_t)NBUK * CAP * 4);
    unsigned int* cbin = (unsigned int*)p; p += align256((size_t)NC * CAPC * 4);
    __bf16* Whi    = (__bf16*)p; p += align256((size_t)8192 * 2);

    prep<<<33, 256, 0, stream>>>(W, Whi, fcur, ccur);
    gemm_bin<<<NGEMM + NBIN, 256, 0, stream>>>(feat, Whi, attn_l, attn_r,
                                               src, dst, hb, el, er, ccur, cbin,
                                               N, Ntiles, E, NC);
    refine<<<NC * 2, 256, 0, stream>>>(ccur, cbin, fcur, fbin, NC);
    aggregate<<<NBUK, 256, 0, stream>>>(fcur, fbin, el, er, hb, bias, out, N);
}